// Round 6
// baseline (558.048 us; speedup 1.0000x reference)
//
#include <hip/hip_runtime.h>
#include <hip/hip_bf16.h>
#include <math.h>

// Problem constants
constexpr int N = 10000;
constexpr int E = 160000;
constexpr int B = 16;
constexpr int PC = 625;   // pool partial chunks (= prepool grid)

typedef short bf16x8 __attribute__((ext_vector_type(8)));
typedef float f32x4 __attribute__((ext_vector_type(4)));

__device__ __forceinline__ float silu_f(float x) {
    return x / (1.0f + __expf(-x));
}

// ---------------- K1: embedding h = TP(concat(x,anf), na, W_emb) + b ----------------
__global__ __launch_bounds__(256) void k_embed(
        const float* __restrict__ x, const float* __restrict__ anf,
        const float* __restrict__ na, const float* __restrict__ W,
        const float* __restrict__ b, float* __restrict__ h) {
    int wv = threadIdx.x >> 6;
    int k = threadIdx.x & 63;
    int n = blockIdx.x * 4 + wv;
    float naR[8];
#pragma unroll
    for (int j = 0; j < 8; ++j) naR[j] = na[n * 8 + j];
    float acc = b[k];
#pragma unroll
    for (int i = 0; i < 17; ++i) {
        float xi = (i < 16) ? x[n * 16 + i] : anf[n];
#pragma unroll
        for (int j = 0; j < 8; ++j)
            acc = fmaf(xi * naR[j], W[(i * 8 + j) * 64 + k], acc);
    }
    h[(size_t)n * 64 + k] = acc;
}

// ---------------- fused weight reorder (all 6 reorders in one launch) ----------------
__device__ __forceinline__ void hilo_store(float wv, __hip_bfloat16* hi, __hip_bfloat16* lo, int idx) {
    __hip_bfloat16 hh = __float2bfloat16(wv);
    hi[idx] = hh;
    lo[idx] = __float2bfloat16(wv - __bfloat162float(hh));
}
__device__ __forceinline__ float zr64_val(const float* Wsrc, int idx) {
    int l = idx >> 15;
    int rem = idx & 32767;
    int kk = rem >> 11, nt = (rem >> 9) & 3, c = (rem >> 5) & 15, q = (rem >> 3) & 3, j = rem & 7;
    return Wsrc[(size_t)l * 32768 + (size_t)(kk * 4 + q) * 512 + j * 64 + nt * 16 + c];
}
__device__ __forceinline__ float wu1_val(const float* Wu1, int idx) {
    int l = idx / 67584;
    int rem = idx % 67584;
    int kk = rem / 2048;
    int r2 = rem % 2048;
    int nt = (r2 >> 9) & 3, c = (r2 >> 5) & 15, q = (r2 >> 3) & 3, j = r2 & 7;
    int i = kk * 4 + q;
    return (i < 129) ? Wu1[(size_t)l * 129 * 512 + (size_t)i * 512 + j * 64 + nt * 16 + c] : 0.f;
}
__device__ __forceinline__ float wm1p_val(const float* Wm1, int idx) {
    int l = idx / 98304;
    int rem = idx % 98304;
    int kk = rem / 32768;
    int r2 = rem % 32768;
    int nt = (r2 >> 9) & 63, c = (r2 >> 5) & 15, q = (r2 >> 3) & 3, t = r2 & 7;
    int i = kk * 32 + q * 8 + t;
    int col = nt * 16 + c;
    int part = col >> 9, kd = (col >> 3) & 63, j = col & 7;
    if (i >= 65) return 0.f;
    return Wm1[(size_t)l * 131 * 512 + (size_t)(part ? 65 + i : i) * 512 + j * 64 + kd];
}
__global__ __launch_bounds__(256) void k_reorder(
        const float* __restrict__ Wm2, const float* __restrict__ Wu2,
        const float* __restrict__ Wp1, const float* __restrict__ Wp2,
        const float* __restrict__ Wu1, const float* __restrict__ Wm1,
        __hip_bfloat16* W2hi, __hip_bfloat16* W2lo,
        __hip_bfloat16* Wu2hi, __hip_bfloat16* Wu2lo,
        __hip_bfloat16* Wp1hi, __hip_bfloat16* Wp1lo,
        __hip_bfloat16* Wp2hi, __hip_bfloat16* Wp2lo,
        __hip_bfloat16* Wu1hi, __hip_bfloat16* Wu1lo,
        __hip_bfloat16* Wm1phi, __hip_bfloat16* Wm1plo) {
    int idx = blockIdx.x * 256 + threadIdx.x;
    if (idx < 65536)        hilo_store(zr64_val(Wm2, idx), W2hi, W2lo, idx);
    else if (idx < 131072) { int i2 = idx - 65536;  hilo_store(zr64_val(Wu2, i2), Wu2hi, Wu2lo, i2); }
    else if (idx < 163840) { int i2 = idx - 131072; hilo_store(zr64_val(Wp1, i2), Wp1hi, Wp1lo, i2); }
    else if (idx < 196608) { int i2 = idx - 163840; hilo_store(zr64_val(Wp2, i2), Wp2hi, Wp2lo, i2); }
    else if (idx < 331776) { int i2 = idx - 196608; hilo_store(wu1_val(Wu1, i2), Wu1hi, Wu1lo, i2); }
    else if (idx < 528384) { int i2 = idx - 331776; hilo_store(wm1p_val(Wm1, i2), Wm1phi, Wm1plo, i2); }
}

// ---------------- K2: precompute P = ha @ B (MFMA, 16 nodes, 8 waves split Nout) + zero agg ----------------
__global__ __launch_bounds__(512, 4) void k_pre_mfma(
        const float* __restrict__ h, const float* __restrict__ anf,
        const __hip_bfloat16* __restrict__ Bhi, const __hip_bfloat16* __restrict__ Blo,
        __hip_bfloat16* __restrict__ P, float* __restrict__ agg) {
    __shared__ __align__(16) __hip_bfloat16 ha_s[16 * 96];
    int tid = threadIdx.x;
    int w = tid >> 6, l = tid & 63;
    int n0 = blockIdx.x * 16;
    // zero this block's slice of agg (625*1024 == N*64)
    float4 z4 = {0.f, 0.f, 0.f, 0.f};
    if (tid < 256) ((float4*)(agg + (size_t)blockIdx.x * 1024))[tid] = z4;
    for (int idx = tid; idx < 16 * 96; idx += 512) {
        int r = idx / 96, c = idx % 96;
        float v = (c < 64) ? h[(size_t)(n0 + r) * 64 + c] : (c == 64 ? anf[n0 + r] : 0.f);
        ha_s[idx] = __float2bfloat16(v);
    }
    __syncthreads();
    int c16 = l & 15, q = l >> 4;
    bf16x8 aF[3];
#pragma unroll
    for (int kk = 0; kk < 3; ++kk)
        aF[kk] = *(const bf16x8*)&ha_s[c16 * 96 + kk * 32 + q * 8];
    int lofs = (c16 * 4 + q) * 8;
    f32x4 zero4 = {0.f, 0.f, 0.f, 0.f};
    f32x4 acc[8];
#pragma unroll
    for (int t = 0; t < 8; ++t) acc[t] = zero4;
#pragma unroll
    for (int kk = 0; kk < 3; ++kk) {
#pragma unroll
        for (int nt2 = 0; nt2 < 8; ++nt2) {
            int nt = w * 8 + nt2;
            bf16x8 bh = *(const bf16x8*)(Bhi + (size_t)(kk * 64 + nt) * 512 + lofs);
            bf16x8 bl = *(const bf16x8*)(Blo + (size_t)(kk * 64 + nt) * 512 + lofs);
            acc[nt2] = __builtin_amdgcn_mfma_f32_16x16x32_bf16(aF[kk], bh, acc[nt2], 0, 0, 0);
            acc[nt2] = __builtin_amdgcn_mfma_f32_16x16x32_bf16(aF[kk], bl, acc[nt2], 0, 0, 0);
        }
    }
#pragma unroll
    for (int nt2 = 0; nt2 < 8; ++nt2)
#pragma unroll
        for (int r = 0; r < 4; ++r) {
            int n = n0 + q * 4 + r;
            P[(size_t)n * 1024 + (w * 8 + nt2) * 16 + c16] = __float2bfloat16(acc[nt2][r]);
        }
}

// ---------------- K3: edge kernel (R5-proven; only occupancy bound raised) ----------------
constexpr int MS = 72;
__global__ __launch_bounds__(256, 5) void k_edge(
        const int* __restrict__ eidx, const float* __restrict__ ea,
        const float* __restrict__ amf, const __hip_bfloat16* __restrict__ P,
        const float* __restrict__ Wm1_l, const float* __restrict__ bm1_l,
        const __hip_bfloat16* __restrict__ W2hi, const __hip_bfloat16* __restrict__ W2lo,
        const float* __restrict__ bm2_l, float* __restrict__ agg) {
    __shared__ __align__(16) __hip_bfloat16 m_s[128 * MS];
    __shared__ float ea_s[128][9];
    __shared__ float amf_s[128];
    __shared__ int src_s[128], dst_s[128];
    __shared__ float bm1_s[64], bm2_s[64];
    int tid = threadIdx.x;
    int l = tid & 63, w = tid >> 6;
    int e0 = blockIdx.x * 128;
    for (int idx = tid; idx < 128; idx += 256) {
        src_s[idx] = eidx[e0 + idx];
        dst_s[idx] = eidx[E + e0 + idx];
        amf_s[idx] = amf[e0 + idx];
    }
    for (int idx = tid; idx < 1024; idx += 256) ea_s[idx >> 3][idx & 7] = ea[(size_t)e0 * 8 + idx];
    if (tid < 64) { bm1_s[tid] = bm1_l[tid]; bm2_s[tid] = bm2_l[tid]; }
    float w130R[8];
#pragma unroll
    for (int j = 0; j < 8; ++j) w130R[j] = Wm1_l[130 * 512 + j * 64 + l];
    __syncthreads();

    // ---- phase 1: m = bf16(silu(m1)), 2 vector loads per edge ----
    float bm1k = bm1_s[l];
#pragma unroll 4
    for (int q = 0; q < 32; ++q) {
        int le = w * 32 + q;
        bf16x8 p1 = *(const bf16x8*)(P + (size_t)dst_s[le] * 1024 + l * 8);
        bf16x8 p2 = *(const bf16x8*)(P + (size_t)src_s[le] * 1024 + 512 + l * 8);
        float amfe = amf_s[le];
        float macc = bm1k;
#pragma unroll
        for (int j = 0; j < 8; ++j) {
            union { short s; __hip_bfloat16 b; } u1c, u2c;
            u1c.s = p1[j]; u2c.s = p2[j];
            float s = __bfloat162float(u1c.b) + __bfloat162float(u2c.b) + amfe * w130R[j];
            macc = fmaf(ea_s[le][j], s, macc);
        }
        m_s[le * MS + l] = __float2bfloat16(silu_f(macc));
    }
    __syncthreads();

    // ---- phase 2: z-GEMM  D[e][kd] = sum_ij (m[e][i]*ea[e][j]) * W2flat[ij][kd] ----
    int c16 = l & 15, q = l >> 4;
    int e0w = w * 32;
    float eaA[2][8];
#pragma unroll
    for (int mt = 0; mt < 2; ++mt)
#pragma unroll
        for (int j = 0; j < 8; ++j) eaA[mt][j] = ea_s[e0w + mt * 16 + c16][j];

    f32x4 acc[2][4];
    f32x4 zero4 = {0.f, 0.f, 0.f, 0.f};
#pragma unroll
    for (int mt = 0; mt < 2; ++mt)
#pragma unroll
        for (int nt = 0; nt < 4; ++nt) acc[mt][nt] = zero4;

    int lofs = (c16 * 4 + q) * 8;
#pragma unroll 2
    for (int kk = 0; kk < 16; ++kk) {
        bf16x8 bh[4], bl[4];
#pragma unroll
        for (int nt = 0; nt < 4; ++nt) {
            int off = (kk * 4 + nt) * 512 + lofs;
            bh[nt] = *(const bf16x8*)(W2hi + off);
            bl[nt] = *(const bf16x8*)(W2lo + off);
        }
#pragma unroll
        for (int mt = 0; mt < 2; ++mt) {
            float mv = __bfloat162float(m_s[(e0w + mt * 16 + c16) * MS + kk * 4 + q]);
            union { bf16x8 v; __hip_bfloat16 h[8]; } au;
#pragma unroll
            for (int j = 0; j < 8; ++j) au.h[j] = __float2bfloat16(mv * eaA[mt][j]);
#pragma unroll
            for (int nt = 0; nt < 4; ++nt) {
                acc[mt][nt] = __builtin_amdgcn_mfma_f32_16x16x32_bf16(au.v, bh[nt], acc[mt][nt], 0, 0, 0);
                acc[mt][nt] = __builtin_amdgcn_mfma_f32_16x16x32_bf16(au.v, bl[nt], acc[mt][nt], 0, 0, 0);
            }
        }
    }
#pragma unroll
    for (int mt = 0; mt < 2; ++mt)
#pragma unroll
        for (int nt = 0; nt < 4; ++nt) {
            int kd = nt * 16 + c16;
            float bias = bm2_s[kd];
#pragma unroll
            for (int r = 0; r < 4; ++r) {
                int e = e0w + mt * 16 + q * 4 + r;
                float v = silu_f(bias + acc[mt][nt][r]);
                atomicAdd(&agg[(size_t)dst_s[e] * 64 + kd], v);
            }
        }
}

// ---------------- K4: node update, fused z-GEMMs, 8 waves split K + LDS reduce ----------------
__global__ __launch_bounds__(512, 4) void k_upd_mfma(
        const float* __restrict__ h_in, const float* __restrict__ anf,
        const float* __restrict__ na, const float* __restrict__ agg,
        const __hip_bfloat16* __restrict__ W1hi, const __hip_bfloat16* __restrict__ W1lo,
        const float* __restrict__ bu1_l,
        const __hip_bfloat16* __restrict__ W2hi_, const __hip_bfloat16* __restrict__ W2lo_,
        const float* __restrict__ bu2_l,
        float* __restrict__ h) {
    __shared__ __align__(16) __hip_bfloat16 xa_s[16 * 136];
    __shared__ __align__(16) __hip_bfloat16 u1_s[16 * 72];
    __shared__ float part_s[8][16][64];
    int tid = threadIdx.x;
    int w = tid >> 6, l = tid & 63;
    int n0 = blockIdx.x * 16;
    for (int idx = tid; idx < 16 * 132; idx += 512) {
        int r = idx / 132, c = idx % 132;
        int n = n0 + r;
        float v;
        if (c < 64) v = h_in[(size_t)n * 64 + c];
        else if (c == 64) v = anf[n];
        else if (c < 129) v = agg[(size_t)n * 64 + (c - 65)];
        else v = 0.f;
        xa_s[r * 136 + c] = __float2bfloat16(v);
    }
    int c16 = l & 15, q = l >> 4;
    float naA[8];
#pragma unroll
    for (int j = 0; j < 8; ++j) naA[j] = na[(size_t)(n0 + c16) * 8 + j];
    __syncthreads();
    int lofs = (c16 * 4 + q) * 8;
    f32x4 zero4 = {0.f, 0.f, 0.f, 0.f};
    f32x4 acc[4];
#pragma unroll
    for (int nt = 0; nt < 4; ++nt) acc[nt] = zero4;
    for (int kk = w; kk < 33; kk += 8) {
        bf16x8 bh[4], bl[4];
#pragma unroll
        for (int nt = 0; nt < 4; ++nt) {
            int off = (kk * 4 + nt) * 512 + lofs;
            bh[nt] = *(const bf16x8*)(W1hi + off);
            bl[nt] = *(const bf16x8*)(W1lo + off);
        }
        float mv = __bfloat162float(xa_s[c16 * 136 + kk * 4 + q]);
        union { bf16x8 v; __hip_bfloat16 hx[8]; } au;
#pragma unroll
        for (int j = 0; j < 8; ++j) au.hx[j] = __float2bfloat16(mv * naA[j]);
#pragma unroll
        for (int nt = 0; nt < 4; ++nt) {
            acc[nt] = __builtin_amdgcn_mfma_f32_16x16x32_bf16(au.v, bh[nt], acc[nt], 0, 0, 0);
            acc[nt] = __builtin_amdgcn_mfma_f32_16x16x32_bf16(au.v, bl[nt], acc[nt], 0, 0, 0);
        }
    }
#pragma unroll
    for (int nt = 0; nt < 4; ++nt)
#pragma unroll
        for (int r = 0; r < 4; ++r) part_s[w][q * 4 + r][nt * 16 + c16] = acc[nt][r];
    __syncthreads();
    for (int t = tid; t < 1024; t += 512) {
        int row = t >> 6, col = t & 63;
        float v = bu1_l[col];
#pragma unroll
        for (int ww = 0; ww < 8; ++ww) v += part_s[ww][row][col];
        u1_s[row * 72 + col] = __float2bfloat16(silu_f(v));
    }
    __syncthreads();
    f32x4 acc2[4];
#pragma unroll
    for (int nt = 0; nt < 4; ++nt) acc2[nt] = zero4;
    for (int kk = w; kk < 16; kk += 8) {
        bf16x8 bh[4], bl[4];
#pragma unroll
        for (int nt = 0; nt < 4; ++nt) {
            int off = (kk * 4 + nt) * 512 + lofs;
            bh[nt] = *(const bf16x8*)(W2hi_ + off);
            bl[nt] = *(const bf16x8*)(W2lo_ + off);
        }
        float mv = __bfloat162float(u1_s[c16 * 72 + kk * 4 + q]);
        union { bf16x8 v; __hip_bfloat16 hx[8]; } au;
#pragma unroll
        for (int j = 0; j < 8; ++j) au.hx[j] = __float2bfloat16(mv * naA[j]);
#pragma unroll
        for (int nt = 0; nt < 4; ++nt) {
            acc2[nt] = __builtin_amdgcn_mfma_f32_16x16x32_bf16(au.v, bh[nt], acc2[nt], 0, 0, 0);
            acc2[nt] = __builtin_amdgcn_mfma_f32_16x16x32_bf16(au.v, bl[nt], acc2[nt], 0, 0, 0);
        }
    }
    __syncthreads();
#pragma unroll
    for (int nt = 0; nt < 4; ++nt)
#pragma unroll
        for (int r = 0; r < 4; ++r) part_s[w][q * 4 + r][nt * 16 + c16] = acc2[nt][r];
    __syncthreads();
    for (int t = tid; t < 1024; t += 512) {
        int row = t >> 6, col = t & 63;
        float v = bu2_l[col];
#pragma unroll
        for (int ww = 0; ww < 8; ++ww) v += part_s[ww][row][col];
        h[(size_t)(n0 + row) * 64 + col] += v;
    }
}

// ---------------- K6: prepool, fused z-GEMMs + in-block pooling (no p2, no global atomics) ----------------
__global__ __launch_bounds__(512, 4) void k_prepool_mfma(
        const float* __restrict__ h, const float* __restrict__ na,
        const int* __restrict__ batch,
        const __hip_bfloat16* __restrict__ W1hi, const __hip_bfloat16* __restrict__ W1lo,
        const float* __restrict__ bp1,
        const __hip_bfloat16* __restrict__ W2hi_, const __hip_bfloat16* __restrict__ W2lo_,
        const float* __restrict__ bp2,
        float* __restrict__ partial_p, float* __restrict__ partial_cnt) {
    __shared__ __align__(16) __hip_bfloat16 xa_s[16 * 72];
    __shared__ __align__(16) __hip_bfloat16 u1_s[16 * 72];
    __shared__ float part_s[8][16][64];
    __shared__ float pool_s[16][64];
    __shared__ float cnt_s[16];
    __shared__ int batch_s[16];
    int tid = threadIdx.x;
    int w = tid >> 6, l = tid & 63;
    int n0 = blockIdx.x * 16;
    for (int idx = tid; idx < 1024; idx += 512) pool_s[idx >> 6][idx & 63] = 0.f;
    if (tid < 16) { cnt_s[tid] = 0.f; batch_s[tid] = batch[n0 + tid]; }
    for (int idx = tid; idx < 16 * 64; idx += 512) {
        int r = idx >> 6, c = idx & 63;
        xa_s[r * 72 + c] = __float2bfloat16(h[(size_t)(n0 + r) * 64 + c]);
    }
    int c16 = l & 15, q = l >> 4;
    float naA[8];
#pragma unroll
    for (int j = 0; j < 8; ++j) naA[j] = na[(size_t)(n0 + c16) * 8 + j];
    __syncthreads();
    if (tid < 16) atomicAdd(&cnt_s[batch_s[tid]], 1.0f);
    int lofs = (c16 * 4 + q) * 8;
    f32x4 zero4 = {0.f, 0.f, 0.f, 0.f};
    f32x4 acc[4];
#pragma unroll
    for (int nt = 0; nt < 4; ++nt) acc[nt] = zero4;
    for (int kk = w; kk < 16; kk += 8) {
        bf16x8 bh[4], bl[4];
#pragma unroll
        for (int nt = 0; nt < 4; ++nt) {
            int off = (kk * 4 + nt) * 512 + lofs;
            bh[nt] = *(const bf16x8*)(W1hi + off);
            bl[nt] = *(const bf16x8*)(W1lo + off);
        }
        float mv = __bfloat162float(xa_s[c16 * 72 + kk * 4 + q]);
        union { bf16x8 v; __hip_bfloat16 hx[8]; } au;
#pragma unroll
        for (int j = 0; j < 8; ++j) au.hx[j] = __float2bfloat16(mv * naA[j]);
#pragma unroll
        for (int nt = 0; nt < 4; ++nt) {
            acc[nt] = __builtin_amdgcn_mfma_f32_16x16x32_bf16(au.v, bh[nt], acc[nt], 0, 0, 0);
            acc[nt] = __builtin_amdgcn_mfma_f32_16x16x32_bf16(au.v, bl[nt], acc[nt], 0, 0, 0);
        }
    }
#pragma unroll
    for (int nt = 0; nt < 4; ++nt)
#pragma unroll
        for (int r = 0; r < 4; ++r) part_s[w][q * 4 + r][nt * 16 + c16] = acc[nt][r];
    __syncthreads();
    for (int t = tid; t < 1024; t += 512) {
        int row = t >> 6, col = t & 63;
        float v = bp1[col];
#pragma unroll
        for (int ww = 0; ww < 8; ++ww) v += part_s[ww][row][col];
        u1_s[row * 72 + col] = __float2bfloat16(silu_f(v));
    }
    __syncthreads();
    f32x4 acc2[4];
#pragma unroll
    for (int nt = 0; nt < 4; ++nt) acc2[nt] = zero4;
    for (int kk = w; kk < 16; kk += 8) {
        bf16x8 bh[4], bl[4];
#pragma unroll
        for (int nt = 0; nt < 4; ++nt) {
            int off = (kk * 4 + nt) * 512 + lofs;
            bh[nt] = *(const bf16x8*)(W2hi_ + off);
            bl[nt] = *(const bf16x8*)(W2lo_ + off);
        }
        float mv = __bfloat162float(u1_s[c16 * 72 + kk * 4 + q]);
        union { bf16x8 v; __hip_bfloat16 hx[8]; } au;
#pragma unroll
        for (int j = 0; j < 8; ++j) au.hx[j] = __float2bfloat16(mv * naA[j]);
#pragma unroll
        for (int nt = 0; nt < 4; ++nt) {
            acc2[nt] = __builtin_amdgcn_mfma_f32_16x16x32_bf16(au.v, bh[nt], acc2[nt], 0, 0, 0);
            acc2[nt] = __builtin_amdgcn_mfma_f32_16x16x32_bf16(au.v, bl[nt], acc2[nt], 0, 0, 0);
        }
    }
    __syncthreads();
#pragma unroll
    for (int nt = 0; nt < 4; ++nt)
#pragma unroll
        for (int r = 0; r < 4; ++r) part_s[w][q * 4 + r][nt * 16 + c16] = acc2[nt][r];
    __syncthreads();
    for (int t = tid; t < 1024; t += 512) {
        int row = t >> 6, col = t & 63;
        float v = bp2[col];
#pragma unroll
        for (int ww = 0; ww < 8; ++ww) v += part_s[ww][row][col];
        atomicAdd(&pool_s[batch_s[row]][col], v);
    }
    __syncthreads();
    for (int t = tid; t < 1024; t += 512)
        partial_p[(size_t)blockIdx.x * 1024 + t] = pool_s[t >> 6][t & 63];
    if (tid < 16) partial_cnt[blockIdx.x * 16 + tid] = cnt_s[tid];
}

// ---------------- K7: reduce 625 partials, mean, final MLP (one block per graph) ----------------
__global__ __launch_bounds__(256) void k_final(
        const float* __restrict__ partial_p, const float* __restrict__ partial_cnt,
        const float* __restrict__ Wq1, const float* __restrict__ bq1,
        const float* __restrict__ Wq2, const float* __restrict__ bq2,
        float* __restrict__ out) {
    __shared__ float red[4][64];
    __shared__ float cred[4];
    __shared__ float g_s[64];
    int b = blockIdx.x;
    int tid = threadIdx.x;
    int k = tid & 63, part = tid >> 6;
    float s = 0.f;
    for (int c = part; c < PC; c += 4) s += partial_p[(size_t)c * 1024 + b * 64 + k];
    red[part][k] = s;
    if (k == 0) {
        float cc = 0.f;
        for (int c = part; c < PC; c += 4) cc += partial_cnt[c * 16 + b];
        cred[part] = cc;
    }
    __syncthreads();
    if (tid < 64) {
        float cnt = cred[0] + cred[1] + cred[2] + cred[3];
        g_s[k] = (red[0][k] + red[1][k] + red[2][k] + red[3][k]) / fmaxf(cnt, 1.0f);
    }
    __syncthreads();
    if (tid < 64) {
        float acc = bq1[k];
#pragma unroll
        for (int i = 0; i < 64; ++i) acc = fmaf(g_s[i], Wq1[i * 64 + k], acc);
        float v = silu_f(acc) * Wq2[k];
#pragma unroll
        for (int off = 32; off > 0; off >>= 1) v += __shfl_down(v, off, 64);
        if (k == 0) out[b] = v + bq2[0];
    }
}

extern "C" void kernel_launch(void* const* d_in, const int* in_sizes, int n_in,
                              void* d_out, int out_size, void* d_ws, size_t ws_size,
                              hipStream_t stream) {
    const float* x    = (const float*)d_in[0];
    const int*   eidx = (const int*)  d_in[1];
    const float* ea   = (const float*)d_in[2];
    const float* na   = (const float*)d_in[3];
    const float* amf  = (const float*)d_in[4];
    const float* anf  = (const float*)d_in[5];
    const int*   batch= (const int*)  d_in[6];
    const float* W_emb= (const float*)d_in[7];
    const float* b_emb= (const float*)d_in[8];
    const float* Wm1  = (const float*)d_in[9];
    const float* bm1  = (const float*)d_in[10];
    const float* Wm2  = (const float*)d_in[11];
    const float* bm2  = (const float*)d_in[12];
    const float* Wu1  = (const float*)d_in[13];
    const float* bu1  = (const float*)d_in[14];
    const float* Wu2  = (const float*)d_in[15];
    const float* bu2  = (const float*)d_in[16];
    const float* Wp1  = (const float*)d_in[17];
    const float* bp1  = (const float*)d_in[18];
    const float* Wp2  = (const float*)d_in[19];
    const float* bp2  = (const float*)d_in[20];
    const float* Wq1  = (const float*)d_in[21];
    const float* bq1  = (const float*)d_in[22];
    const float* Wq2  = (const float*)d_in[23];
    const float* bq2  = (const float*)d_in[24];

    float* ws = (float*)d_ws;
    float* h      = ws;                           // N*64
    float* agg    = h + (size_t)N * 64;           // N*64
    float* part_p = agg + (size_t)N * 64;         // PC*1024
    float* part_c = part_p + (size_t)PC * 1024;   // PC*16
    float* fend   = part_c + PC * 16;
    __hip_bfloat16* Pb     = (__hip_bfloat16*)fend;          // N*1024
    __hip_bfloat16* W2hi   = Pb + (size_t)N * 1024;
    __hip_bfloat16* W2lo   = W2hi + 65536;
    __hip_bfloat16* Wu2hi  = W2lo + 65536;
    __hip_bfloat16* Wu2lo  = Wu2hi + 65536;
    __hip_bfloat16* Wp1hi  = Wu2lo + 65536;
    __hip_bfloat16* Wp1lo  = Wp1hi + 32768;
    __hip_bfloat16* Wp2hi  = Wp1lo + 32768;
    __hip_bfloat16* Wp2lo  = Wp2hi + 32768;
    __hip_bfloat16* Wu1hi  = Wp2lo + 32768;
    __hip_bfloat16* Wu1lo  = Wu1hi + 135168;
    __hip_bfloat16* Wm1phi = Wu1lo + 135168;
    __hip_bfloat16* Wm1plo = Wm1phi + 196608;

    k_embed<<<N / 4, 256, 0, stream>>>(x, anf, na, W_emb, b_emb, h);
    k_reorder<<<2064, 256, 0, stream>>>(Wm2, Wu2, Wp1, Wp2, Wu1, Wm1,
                                        W2hi, W2lo, Wu2hi, Wu2lo, Wp1hi, Wp1lo,
                                        Wp2hi, Wp2lo, Wu1hi, Wu1lo, Wm1phi, Wm1plo);

    for (int l = 0; l < 2; ++l) {
        k_pre_mfma<<<625, 512, 0, stream>>>(h, anf,
                                            Wm1phi + (size_t)l * 98304, Wm1plo + (size_t)l * 98304,
                                            Pb, agg);
        k_edge<<<E / 128, 256, 0, stream>>>(eidx, ea, amf, Pb,
                                            Wm1 + (size_t)l * 131 * 512, bm1 + l * 64,
                                            W2hi + (size_t)l * 32768, W2lo + (size_t)l * 32768,
                                            bm2 + l * 64, agg);
        k_upd_mfma<<<625, 512, 0, stream>>>(h, anf, na, agg,
                                            Wu1hi + (size_t)l * 67584, Wu1lo + (size_t)l * 67584,
                                            bu1 + l * 64,
                                            Wu2hi + (size_t)l * 32768, Wu2lo + (size_t)l * 32768,
                                            bu2 + l * 64, h);
    }
    k_prepool_mfma<<<625, 512, 0, stream>>>(h, na, batch, Wp1hi, Wp1lo, bp1,
                                            Wp2hi, Wp2lo, bp2, part_p, part_c);
    k_final<<<B, 256, 0, stream>>>(part_p, part_c, Wq1, bq1, Wq2, bq2, (float*)d_out);
}